// Round 1
// baseline (328.346 us; speedup 1.0000x reference)
//
#include <hip/hip_runtime.h>

#define VOCAB 30000
#define MPAD  30080   // 235 * 128
#define MT_PAD 240    // m-tiles padded to multiple of 8 (XCD count)

typedef __attribute__((ext_vector_type(8))) short bf16x8;
typedef __attribute__((ext_vector_type(4))) float f32x4;

__device__ __forceinline__ unsigned short f2bf(float f) {
    unsigned int u = __builtin_bit_cast(unsigned int, f);
    u += 0x7fffu + ((u >> 16) & 1u);          // round-to-nearest-even
    return (unsigned short)(u >> 16);
}
__device__ __forceinline__ float bf2f(unsigned int h) {
    unsigned int u = h << 16;
    return __builtin_bit_cast(float, u);
}

__device__ __forceinline__ void async16(const void* g, void* l) {
    __builtin_amdgcn_global_load_lds(
        (__attribute__((address_space(1))) void*)g,
        (__attribute__((address_space(3))) void*)l, 16, 0, 0);
}

// ---------------- compaction ----------------
// flags relies on the harness's 0xAA ws poison: "marked" == exactly 1.
__global__ void k_mark(const int* __restrict__ ingrs, const int* __restrict__ lengths,
                       int* __restrict__ flags, int* __restrict__ cnt)
{
    const int i = blockIdx.x * 256 + threadIdx.x;
    if (i == 0) *cnt = 0;
    if (i >= 4096 * 20) return;
    const int b = i / 20;
    const int l = i - b * 20;
    if (l < lengths[b]) flags[ingrs[i]] = 1;
}

__global__ void k_assign(const int* __restrict__ flags, int* __restrict__ remap,
                         int* __restrict__ cnt)
{
    const int i = blockIdx.x * 256 + threadIdx.x;
    if (i < VOCAB && flags[i] == 1) remap[i] = atomicAdd(cnt, 1);
}

// ---------------- shared device bodies ----------------

__device__ __forceinline__ void transpose_body(
    const float* __restrict__ in, unsigned short* __restrict__ out,
    int K, int Nin, int n0, int k0, int tid, float (*t)[65])
{
#pragma unroll
    for (int p = 0; p < 16; ++p) {
        const int lin = p * 256 + tid;
        const int kk = lin >> 6, nn = lin & 63;
        const int n = n0 + nn;
        t[kk][nn] = (n < Nin) ? in[(size_t)(k0 + kk) * Nin + n] : 0.f;
    }
    __syncthreads();
#pragma unroll
    for (int p = 0; p < 16; ++p) {
        const int lin = p * 256 + tid;
        const int nn = lin >> 6, kk = lin & 63;
        out[(size_t)(n0 + nn) * K + k0 + kk] = f2bf(t[kk][nn]);
    }
}

// m97-style BK=64 XOR-swizzled MFMA GEMM tile; id pre-swizzled by caller.
__device__ __forceinline__ void gemm_body(
    unsigned short* smem,
    const unsigned short* __restrict__ A, const unsigned short* __restrict__ BT,
    const float* __restrict__ bias, int bias_n, unsigned short* __restrict__ C,
    int K, int N, int relu, int mc, int id, int nt_shift)
{
    const int w  = id >> 3;
    const int n_tile = w & ((1 << nt_shift) - 1);
    const int m_tile = (id & 7) + ((w >> nt_shift) << 3);
    const int m0 = m_tile * 128;
    if (m0 >= mc) return;
    const int n0 = n_tile * 128;

    unsigned short* As = smem;
    unsigned short* Bs = smem + 8192;

    const int tid  = threadIdx.x;
    const int lane = tid & 63;
    const int wid  = tid >> 6;
    const int wr   = wid >> 1;
    const int wc   = wid & 1;
    const int q  = lane >> 4;
    const int ml = lane & 15;

    f32x4 acc[4][4];
    const f32x4 zero = {0.f, 0.f, 0.f, 0.f};
#pragma unroll
    for (int i = 0; i < 4; ++i)
#pragma unroll
        for (int j = 0; j < 4; ++j) acc[i][j] = zero;

    // staging: wave w stages groups 4w..4w+3 (8 rows each) of A and B.
    // LDS row r holds its 8 16-B k-chunks permuted: chunk kc at pos kc^(r&7).
    const int rg = lane >> 3;
    const int kc = (lane & 7) ^ rg;
    const unsigned short* pA = A  + (size_t)(m0 + wid * 32 + rg) * K + kc * 8;
    const unsigned short* pB = BT + (size_t)(n0 + wid * 32 + rg) * K + kc * 8;
    unsigned short* lA = &As[wid * 4 * 512 + lane * 8];
    unsigned short* lB = &Bs[wid * 4 * 512 + lane * 8];

    const int swz0 = (q ^ (ml & 7)) * 8;

    for (int k0 = 0; k0 < K; k0 += 64) {
#pragma unroll
        for (int gg = 0; gg < 4; ++gg) {
            async16(pA + (size_t)gg * 8 * K, lA + gg * 512);
            async16(pB + (size_t)gg * 8 * K, lB + gg * 512);
        }
        pA += 64; pB += 64;
        __syncthreads();

        bf16x8 af[4], bfr[4];
#pragma unroll
        for (int t = 0; t < 4; ++t) {
            af[t]  = *(const bf16x8*)&As[(wr * 64 + t * 16 + ml) * 64 + swz0];
            bfr[t] = *(const bf16x8*)&Bs[(wc * 64 + t * 16 + ml) * 64 + swz0];
        }
#pragma unroll
        for (int i = 0; i < 4; ++i)
#pragma unroll
            for (int j = 0; j < 4; ++j)
                acc[i][j] = __builtin_amdgcn_mfma_f32_16x16x32_bf16(
                    af[i], bfr[j], acc[i][j], 0, 0, 0);
#pragma unroll
        for (int t = 0; t < 4; ++t) {
            af[t]  = *(const bf16x8*)&As[(wr * 64 + t * 16 + ml) * 64 + (swz0 ^ 32)];
            bfr[t] = *(const bf16x8*)&Bs[(wc * 64 + t * 16 + ml) * 64 + (swz0 ^ 32)];
        }
#pragma unroll
        for (int i = 0; i < 4; ++i)
#pragma unroll
            for (int j = 0; j < 4; ++j)
                acc[i][j] = __builtin_amdgcn_mfma_f32_16x16x32_bf16(
                    af[i], bfr[j], acc[i][j], 0, 0, 0);

        __syncthreads();
    }

    // epilogue phase 1: bias/relu/round into LDS (stride 136 shorts)
#pragma unroll
    for (int i = 0; i < 4; ++i) {
#pragma unroll
        for (int j = 0; j < 4; ++j) {
#pragma unroll
            for (int r = 0; r < 4; ++r) {
                const int rl = wr * 64 + i * 16 + q * 4 + r;
                const int cl = wc * 64 + j * 16 + ml;
                float v = acc[i][j][r];
                const int col = n0 + cl;
                v += (col < bias_n) ? bias[col] : 0.f;
                if (relu) v = fmaxf(v, 0.f);
                smem[rl * 136 + cl] = f2bf(v);
            }
        }
    }
    __syncthreads();
    // epilogue phase 2: 16 B/lane coalesced stores
#pragma unroll
    for (int p = 0; p < 8; ++p) {
        const int rr = p * 16 + (tid >> 4);
        const int cc = tid & 15;
        const uint4 val = *(const uint4*)&smem[rr * 136 + cc * 8];
        *(uint4*)&C[(size_t)(m0 + rr) * N + n0 + cc * 8] = val;
    }
}

// ---------------- k_prep: A1 gather-activate | W2 transpose ----------------
__global__ __launch_bounds__(256)
void k_prep(const float* __restrict__ W1, const float* __restrict__ b1,
            const int* __restrict__ flags, const int* __restrict__ remap,
            unsigned short* __restrict__ A1,
            const float* __restrict__ W2, unsigned short* __restrict__ W2T)
{
    __shared__ float t[64][65];
    const int bid = blockIdx.x;
    const int tid = threadIdx.x;

    if (bid < 15000) {                       // 2 vocab rows per block
        const int id = bid * 2 + (tid >> 7);
        if (flags[id] != 1) return;
        const int row = remap[id];
        const int k4  = (tid & 127) * 4;
        const float4 w  = *(const float4*)(W1 + (size_t)id * 512 + k4);
        const float4 bb = *(const float4*)(b1 + k4);
        unsigned short o[4];
        o[0] = f2bf(fmaxf(w.x + bb.x, 0.f));
        o[1] = f2bf(fmaxf(w.y + bb.y, 0.f));
        o[2] = f2bf(fmaxf(w.z + bb.z, 0.f));
        o[3] = f2bf(fmaxf(w.w + bb.w, 0.f));
        *(uint2*)(A1 + (size_t)row * 512 + k4) = *(const uint2*)o;
    } else {                                 // W2 [512x1024] -> W2T [1024x512]
        const int local = bid - 15000;
        transpose_body(W2, W2T, 512, 1024, (local & 15) * 64, (local >> 4) * 64, tid, t);
    }
}

// ---------------- k_gemm1: GEMM1 + piggybacked W3 transpose + slots --------
__global__ __launch_bounds__(256)
void k_gemm1(const unsigned short* __restrict__ A1, const unsigned short* __restrict__ W2T,
             const float* __restrict__ b2, unsigned short* __restrict__ H2,
             const int* __restrict__ cnt,
             const float* __restrict__ W3, unsigned short* __restrict__ W3T,
             const int* __restrict__ ingrs, const int* __restrict__ lengths,
             const int* __restrict__ remap, int* __restrict__ slots)
{
    __shared__ __align__(16) unsigned short smem[128 * 136];
    const int bid = blockIdx.x;
    if (bid < MT_PAD * 8) {                  // GEMM1: H2 = relu(A1 @ W2 + b2)
        const int mc = (*cnt + 127) & ~127;
        gemm_body(smem, A1, W2T, b2, 1024, H2, 512, 1024, 1, mc, bid, 3);
    } else if (bid < MT_PAD * 8 + 512) {     // W3 [1024x2047] -> W3T [2048x1024]
        const int local = bid - MT_PAD * 8;
        transpose_body(W3, W3T, 1024, 2047, (local & 31) * 64, (local >> 5) * 64,
                       threadIdx.x, (float(*)[65])smem);
    } else {                                 // slots[b,l] = remap[ingrs[b,l]]
        const int i = (bid - (MT_PAD * 8 + 512)) * 256 + threadIdx.x;
        if (i < 4096 * 20) {
            const int b = i / 20;
            const int l = i - b * 20;
            if (l < lengths[b]) slots[i] = remap[ingrs[i]];
        }
    }
}

// ---------------- k_gemm2 ----------------
__global__ __launch_bounds__(256)
void k_gemm2(const unsigned short* __restrict__ H2, const unsigned short* __restrict__ W3T,
             const float* __restrict__ b3, unsigned short* __restrict__ Table,
             const int* __restrict__ cnt)
{
    __shared__ __align__(16) unsigned short smem[128 * 136];
    const int mc = (*cnt + 127) & ~127;
    gemm_body(smem, H2, W3T, b3, 2047, Table, 1024, 2048, 0, mc, blockIdx.x, 4);
}

// ---------------- k_gather: one wave per batch row, barrier-free ----------
// lane owns cols { (c*64+lane)*8 .. +8 } for c=0..3 (32 cols). Full-row norm
// via 6-step shfl_xor; no LDS, no __syncthreads.
__global__ __launch_bounds__(64)
void k_gather(const int* __restrict__ lengths, const int* __restrict__ slots,
              const unsigned short* __restrict__ Table, float* __restrict__ out)
{
    const int b    = blockIdx.x;
    const int lane = threadIdx.x;

    float acc[32];
#pragma unroll
    for (int j = 0; j < 32; ++j) acc[j] = 0.f;

    const int len = lengths[b];
    if (len > 0) {
        uint4 u[4];
        {
            const int slot = slots[b * 20];
            const uint4* rp = (const uint4*)(Table + (size_t)slot * 2048);
#pragma unroll
            for (int c = 0; c < 4; ++c) u[c] = rp[c * 64 + lane];
        }
        for (int l = 0; l < len; ++l) {
            uint4 cu[4];
#pragma unroll
            for (int c = 0; c < 4; ++c) cu[c] = u[c];
            if (l + 1 < len) {                       // prefetch next row
                const int ns = slots[b * 20 + l + 1];
                const uint4* rp = (const uint4*)(Table + (size_t)ns * 2048);
#pragma unroll
                for (int c = 0; c < 4; ++c) u[c] = rp[c * 64 + lane];
            }
            float v[32];
#pragma unroll
            for (int c = 0; c < 4; ++c) {
                v[c*8+0] = bf2f(cu[c].x & 0xffffu); v[c*8+1] = bf2f(cu[c].x >> 16);
                v[c*8+2] = bf2f(cu[c].y & 0xffffu); v[c*8+3] = bf2f(cu[c].y >> 16);
                v[c*8+4] = bf2f(cu[c].z & 0xffffu); v[c*8+5] = bf2f(cu[c].z >> 16);
                v[c*8+6] = bf2f(cu[c].w & 0xffffu); v[c*8+7] = bf2f(cu[c].w >> 16);
            }
            float s = 0.f;
#pragma unroll
            for (int j = 0; j < 32; ++j) s += v[j] * v[j];
#pragma unroll
            for (int off = 1; off < 64; off <<= 1) s += __shfl_xor(s, off, 64);
            const float invn = 1.0f / fmaxf(sqrtf(s), 1e-12f);
#pragma unroll
            for (int j = 0; j < 32; ++j) acc[j] += v[j] * invn;
        }
    }

    const size_t base = (size_t)b * 2047;
#pragma unroll
    for (int c = 0; c < 4; ++c) {
        const int col = (c * 64 + lane) * 8;
#pragma unroll
        for (int j = 0; j < 8; ++j)
            if (col + j < 2047) out[base + col + j] = acc[c * 8 + j];
    }
}

// ---------------- launch ----------------

extern "C" void kernel_launch(void* const* d_in, const int* in_sizes, int n_in,
                              void* d_out, int out_size, void* d_ws, size_t ws_size,
                              hipStream_t stream)
{
    const int*   ingrs   = (const int*)d_in[0];
    const int*   lengths = (const int*)d_in[1];
    const float* W1 = (const float*)d_in[2];
    const float* b1 = (const float*)d_in[3];
    const float* W2 = (const float*)d_in[4];
    const float* b2 = (const float*)d_in[5];
    const float* W3 = (const float*)d_in[6];
    const float* b3 = (const float*)d_in[7];
    float* out = (float*)d_out;

    // ws layout (byte offsets, 16B-aligned):
    //   A1    [MPAD x 512]  bf16 :           0 ..  30,801,920
    //   H2    [MPAD x 1024] bf16 :  30,801,920 ..  92,405,760
    //   Table [MPAD x 2048] bf16 :  92,405,760 .. 215,613,440
    //   W2T   [1024 x 512]  bf16 : 215,613,440 .. 216,662,016
    //   W3T   [2048 x 1024] bf16 : 216,662,016 .. 220,856,320
    //   flags [VOCAB] int        : 220,856,320 .. 220,976,320
    //   remap [VOCAB] int        : 220,976,320 .. 221,096,320
    //   cnt   [1] int            : 221,096,320 .. 221,096,324
    //   slots [4096*20] int      : 221,216,448 .. 221,544,128
    char* ws = (char*)d_ws;
    unsigned short* A1    = (unsigned short*)(ws);
    unsigned short* H2    = (unsigned short*)(ws + 30801920);
    unsigned short* Table = (unsigned short*)(ws + 92405760);
    unsigned short* W2T   = (unsigned short*)(ws + 215613440);
    unsigned short* W3T   = (unsigned short*)(ws + 216662016);
    int*            flags = (int*)(ws + 220856320);
    int*            remap = (int*)(ws + 220976320);
    int*            cnt   = (int*)(ws + 221096320);
    int*            slots = (int*)(ws + 221216448);

    k_mark  <<<(4096 * 20 + 255) / 256, 256, 0, stream>>>(ingrs, lengths, flags, cnt);
    k_assign<<<(VOCAB + 255) / 256, 256, 0, stream>>>(flags, remap, cnt);
    // a1c (15000) | W2T (128)
    k_prep<<<15128, 256, 0, stream>>>(W1, b1, flags, remap, A1, W2, W2T);
    // GEMM1 (1920 swizzled) | W3T transpose (512) | slots (320)
    k_gemm1<<<MT_PAD * 8 + 512 + 320, 256, 0, stream>>>(
        A1, W2T, b2, H2, cnt, W3, W3T, ingrs, lengths, remap, slots);
    // GEMM2: Table = H2 @ W3 + b3  (NT=16)
    k_gemm2<<<MT_PAD * 16, 256, 0, stream>>>(H2, W3T, b3, Table, cnt);

    k_gather<<<4096, 64, 0, stream>>>(lengths, slots, Table, out);
}

// Round 2
// 320.477 us; speedup vs baseline: 1.0246x; 1.0246x over previous
//
#include <hip/hip_runtime.h>

#define VOCAB 30000
#define MPAD  30080   // 235 * 128
#define MT_PAD 240    // m-tiles padded to multiple of 8 (XCD count)

typedef __attribute__((ext_vector_type(8))) short bf16x8;
typedef __attribute__((ext_vector_type(4))) float f32x4;

__device__ __forceinline__ unsigned short f2bf(float f) {
    unsigned int u = __builtin_bit_cast(unsigned int, f);
    u += 0x7fffu + ((u >> 16) & 1u);          // round-to-nearest-even
    return (unsigned short)(u >> 16);
}
__device__ __forceinline__ float bf2f(unsigned int h) {
    unsigned int u = h << 16;
    return __builtin_bit_cast(float, u);
}

__device__ __forceinline__ void async16(const void* g, void* l) {
    __builtin_amdgcn_global_load_lds(
        (__attribute__((address_space(1))) void*)g,
        (__attribute__((address_space(3))) void*)l, 16, 0, 0);
}

// ---------------- compaction ----------------
// flags relies on the harness's 0xAA ws poison: "marked" == exactly 1.
__global__ void k_mark(const int* __restrict__ ingrs, const int* __restrict__ lengths,
                       int* __restrict__ flags, int* __restrict__ cnt)
{
    const int i = blockIdx.x * 256 + threadIdx.x;
    if (i == 0) *cnt = 0;
    if (i >= 4096 * 20) return;
    const int b = i / 20;
    const int l = i - b * 20;
    if (l < lengths[b]) flags[ingrs[i]] = 1;
}

__global__ void k_assign(const int* __restrict__ flags, int* __restrict__ remap,
                         int* __restrict__ cnt)
{
    const int i = blockIdx.x * 256 + threadIdx.x;
    if (i < VOCAB && flags[i] == 1) remap[i] = atomicAdd(cnt, 1);
}

// ---------------- shared device bodies ----------------

__device__ __forceinline__ void transpose_body(
    const float* __restrict__ in, unsigned short* __restrict__ out,
    int K, int Nin, int n0, int k0, int tid, float (*t)[65])
{
#pragma unroll
    for (int p = 0; p < 16; ++p) {
        const int lin = p * 256 + tid;
        const int kk = lin >> 6, nn = lin & 63;
        const int n = n0 + nn;
        t[kk][nn] = (n < Nin) ? in[(size_t)(k0 + kk) * Nin + n] : 0.f;
    }
    __syncthreads();
#pragma unroll
    for (int p = 0; p < 16; ++p) {
        const int lin = p * 256 + tid;
        const int nn = lin >> 6, kk = lin & 63;
        out[(size_t)(n0 + nn) * K + k0 + kk] = f2bf(t[kk][nn]);
    }
}

// m97-style BK=64 XOR-swizzled MFMA GEMM tile; id pre-swizzled by caller.
// (kept for GEMM1)
__device__ __forceinline__ void gemm_body(
    unsigned short* smem,
    const unsigned short* __restrict__ A, const unsigned short* __restrict__ BT,
    const float* __restrict__ bias, int bias_n, unsigned short* __restrict__ C,
    int K, int N, int relu, int mc, int id, int nt_shift)
{
    const int w  = id >> 3;
    const int n_tile = w & ((1 << nt_shift) - 1);
    const int m_tile = (id & 7) + ((w >> nt_shift) << 3);
    const int m0 = m_tile * 128;
    if (m0 >= mc) return;
    const int n0 = n_tile * 128;

    unsigned short* As = smem;
    unsigned short* Bs = smem + 8192;

    const int tid  = threadIdx.x;
    const int lane = tid & 63;
    const int wid  = tid >> 6;
    const int wr   = wid >> 1;
    const int wc   = wid & 1;
    const int q  = lane >> 4;
    const int ml = lane & 15;

    f32x4 acc[4][4];
    const f32x4 zero = {0.f, 0.f, 0.f, 0.f};
#pragma unroll
    for (int i = 0; i < 4; ++i)
#pragma unroll
        for (int j = 0; j < 4; ++j) acc[i][j] = zero;

    const int rg = lane >> 3;
    const int kc = (lane & 7) ^ rg;
    const unsigned short* pA = A  + (size_t)(m0 + wid * 32 + rg) * K + kc * 8;
    const unsigned short* pB = BT + (size_t)(n0 + wid * 32 + rg) * K + kc * 8;
    unsigned short* lA = &As[wid * 4 * 512 + lane * 8];
    unsigned short* lB = &Bs[wid * 4 * 512 + lane * 8];

    const int swz0 = (q ^ (ml & 7)) * 8;

    for (int k0 = 0; k0 < K; k0 += 64) {
#pragma unroll
        for (int gg = 0; gg < 4; ++gg) {
            async16(pA + (size_t)gg * 8 * K, lA + gg * 512);
            async16(pB + (size_t)gg * 8 * K, lB + gg * 512);
        }
        pA += 64; pB += 64;
        __syncthreads();

        bf16x8 af[4], bfr[4];
#pragma unroll
        for (int t = 0; t < 4; ++t) {
            af[t]  = *(const bf16x8*)&As[(wr * 64 + t * 16 + ml) * 64 + swz0];
            bfr[t] = *(const bf16x8*)&Bs[(wc * 64 + t * 16 + ml) * 64 + swz0];
        }
#pragma unroll
        for (int i = 0; i < 4; ++i)
#pragma unroll
            for (int j = 0; j < 4; ++j)
                acc[i][j] = __builtin_amdgcn_mfma_f32_16x16x32_bf16(
                    af[i], bfr[j], acc[i][j], 0, 0, 0);
#pragma unroll
        for (int t = 0; t < 4; ++t) {
            af[t]  = *(const bf16x8*)&As[(wr * 64 + t * 16 + ml) * 64 + (swz0 ^ 32)];
            bfr[t] = *(const bf16x8*)&Bs[(wc * 64 + t * 16 + ml) * 64 + (swz0 ^ 32)];
        }
#pragma unroll
        for (int i = 0; i < 4; ++i)
#pragma unroll
            for (int j = 0; j < 4; ++j)
                acc[i][j] = __builtin_amdgcn_mfma_f32_16x16x32_bf16(
                    af[i], bfr[j], acc[i][j], 0, 0, 0);

        __syncthreads();
    }

    // epilogue phase 1: bias/relu/round into LDS (stride 136 shorts)
#pragma unroll
    for (int i = 0; i < 4; ++i) {
#pragma unroll
        for (int j = 0; j < 4; ++j) {
#pragma unroll
            for (int r = 0; r < 4; ++r) {
                const int rl = wr * 64 + i * 16 + q * 4 + r;
                const int cl = wc * 64 + j * 16 + ml;
                float v = acc[i][j][r];
                const int col = n0 + cl;
                v += (col < bias_n) ? bias[col] : 0.f;
                if (relu) v = fmaxf(v, 0.f);
                smem[rl * 136 + cl] = f2bf(v);
            }
        }
    }
    __syncthreads();
#pragma unroll
    for (int p = 0; p < 8; ++p) {
        const int rr = p * 16 + (tid >> 4);
        const int cc = tid & 15;
        const uint4 val = *(const uint4*)&smem[rr * 136 + cc * 8];
        *(uint4*)&C[(size_t)(m0 + rr) * N + n0 + cc * 8] = val;
    }
}

// ---------------- k_prep: A1 gather-activate | W2 transpose ----------------
__global__ __launch_bounds__(256)
void k_prep(const float* __restrict__ W1, const float* __restrict__ b1,
            const int* __restrict__ flags, const int* __restrict__ remap,
            unsigned short* __restrict__ A1,
            const float* __restrict__ W2, unsigned short* __restrict__ W2T)
{
    __shared__ float t[64][65];
    const int bid = blockIdx.x;
    const int tid = threadIdx.x;

    if (bid < 15000) {                       // 2 vocab rows per block
        const int id = bid * 2 + (tid >> 7);
        if (flags[id] != 1) return;
        const int row = remap[id];
        const int k4  = (tid & 127) * 4;
        const float4 w  = *(const float4*)(W1 + (size_t)id * 512 + k4);
        const float4 bb = *(const float4*)(b1 + k4);
        unsigned short o[4];
        o[0] = f2bf(fmaxf(w.x + bb.x, 0.f));
        o[1] = f2bf(fmaxf(w.y + bb.y, 0.f));
        o[2] = f2bf(fmaxf(w.z + bb.z, 0.f));
        o[3] = f2bf(fmaxf(w.w + bb.w, 0.f));
        *(uint2*)(A1 + (size_t)row * 512 + k4) = *(const uint2*)o;
    } else {                                 // W2 [512x1024] -> W2T [1024x512]
        const int local = bid - 15000;
        transpose_body(W2, W2T, 512, 1024, (local & 15) * 64, (local >> 4) * 64, tid, t);
    }
}

// ---------------- k_gemm1: GEMM1 + piggybacked W3 transpose + slots --------
__global__ __launch_bounds__(256)
void k_gemm1(const unsigned short* __restrict__ A1, const unsigned short* __restrict__ W2T,
             const float* __restrict__ b2, unsigned short* __restrict__ H2,
             const int* __restrict__ cnt,
             const float* __restrict__ W3, unsigned short* __restrict__ W3T,
             const int* __restrict__ ingrs, const int* __restrict__ lengths,
             const int* __restrict__ remap, int* __restrict__ slots)
{
    __shared__ __align__(16) unsigned short smem[128 * 136];
    const int bid = blockIdx.x;
    if (bid < MT_PAD * 8) {                  // GEMM1: H2 = relu(A1 @ W2 + b2)
        const int mc = (*cnt + 127) & ~127;
        gemm_body(smem, A1, W2T, b2, 1024, H2, 512, 1024, 1, mc, bid, 3);
    } else if (bid < MT_PAD * 8 + 512) {     // W3 [1024x2047] -> W3T [2048x1024]
        const int local = bid - MT_PAD * 8;
        transpose_body(W3, W3T, 1024, 2047, (local & 31) * 64, (local >> 5) * 64,
                       threadIdx.x, (float(*)[65])smem);
    } else {                                 // slots[b,l] = remap[ingrs[b,l]]
        const int i = (bid - (MT_PAD * 8 + 512)) * 256 + threadIdx.x;
        if (i < 4096 * 20) {
            const int b = i / 20;
            const int l = i - b * 20;
            if (l < lengths[b]) slots[i] = remap[ingrs[i]];
        }
    }
}

// ---------------- k_gemm2: 256x256 tile, 8 waves, dbuf + counted vmcnt -----
// T3+T4 phase schedule (8-phase-family): per K-tile 4 phases of
// {ds_read subtile; s_barrier; lgkmcnt(0)+sched_barrier; setprio(1); 16 MFMA;
//  setprio(0); s_barrier}; tile t+2 staged once per iter AFTER the last
// phase's closing barrier (all waves past their lgkmcnt -> no LDS race);
// main-loop wait is vmcnt(8): tile t+1 complete, tile t+2 stays in flight.
#define G2_NK 16      // K=1024 / BK=64
#define G2_K  1024
#define G2_N  2048
#define G2_MT 120     // padded m-tiles (multiple of 8 XCDs); active: ceil(mc/256)

#define MF(a, b, c) __builtin_amdgcn_mfma_f32_16x16x32_bf16(a, b, c, 0, 0, 0)

__global__ __launch_bounds__(512, 2)
void k_gemm2(const unsigned short* __restrict__ A, const unsigned short* __restrict__ BT,
             const float* __restrict__ bias, unsigned short* __restrict__ C,
             const int* __restrict__ cnt)
{
    __shared__ __align__(16) unsigned short lds[65536];   // 128 KiB: A/B x dbuf

    const int id = blockIdx.x;
    const int w  = id >> 3;
    const int n_tile = w & 7;                 // N=2048 -> 8 n-tiles
    const int m_tile = (id & 7) + ((w >> 3) << 3);  // XCD-banded m
    const int m0 = m_tile * 256;
    const int mc = (*cnt + 255) & ~255;
    if (m0 >= mc) return;
    const int n0 = n_tile * 256;

    const int tid  = threadIdx.x;
    const int lane = tid & 63;
    const int w0   = tid >> 6;                // wave 0..7
    const int wr   = w0 >> 2;                 // 0..1  (128-row half)
    const int wc   = w0 & 3;                  // 0..3  (64-col strip)
    const int q    = lane >> 4;
    const int ml   = lane & 15;
    const int m7   = ml & 7;

    f32x4 acc[8][4];
    const f32x4 zero = {0.f, 0.f, 0.f, 0.f};
#pragma unroll
    for (int i = 0; i < 8; ++i)
#pragma unroll
        for (int j = 0; j < 4; ++j) acc[i][j] = zero;

    // staging: wave w0 stages rows [w0*32, w0*32+32) of A and of BT, 4 calls
    // each, 8 rows per call; global source pre-swizzled (chunk kc at phys lane&7)
    const int rg = lane >> 3;
    const int kc = (lane & 7) ^ rg;
    const unsigned short* pA0 = A  + (size_t)(m0 + w0 * 32 + rg) * G2_K + kc * 8;
    const unsigned short* pB0 = BT + (size_t)(n0 + w0 * 32 + rg) * G2_K + kc * 8;
    const int dstoff = w0 * 2048 + lane * 8;  // shorts; lane*16B per HW rule

#define G2_STAGE(BUF, KT) do {                                             \
        const unsigned short* _sa = pA0 + (size_t)(KT) * 64;               \
        const unsigned short* _sb = pB0 + (size_t)(KT) * 64;               \
        unsigned short* _da = &lds[(BUF) * 16384 + dstoff];                \
        unsigned short* _db = &lds[32768 + (BUF) * 16384 + dstoff];        \
        _Pragma("unroll")                                                  \
        for (int g = 0; g < 4; ++g) {                                      \
            async16(_sa + (size_t)g * 8 * G2_K, _da + g * 512);            \
            async16(_sb + (size_t)g * 8 * G2_K, _db + g * 512);            \
        }                                                                  \
    } while (0)

    // fragment reads: logical chunk (S*4+q), physical = logical ^ (row&7)=^m7
#define LDA(I, S) (*(const bf16x8*)&lds[cb + ((wr * 128 + (I) * 16 + ml) * 64) + ((((S) * 4 + q) ^ m7) * 8)])
#define LDB(J, S) (*(const bf16x8*)&lds[32768 + cb + ((wc * 64 + (J) * 16 + ml) * 64) + ((((S) * 4 + q) ^ m7) * 8)])

#define G2_PHASE(I0) do {                                                  \
        bf16x8 a00 = LDA(I0, 0), a01 = LDA(I0, 1);                         \
        bf16x8 a10 = LDA(I0 + 1, 0), a11 = LDA(I0 + 1, 1);                 \
        __builtin_amdgcn_s_barrier();                                      \
        asm volatile("s_waitcnt lgkmcnt(0)" ::: "memory");                 \
        __builtin_amdgcn_sched_barrier(0);                                 \
        __builtin_amdgcn_s_setprio(1);                                     \
        _Pragma("unroll")                                                  \
        for (int j = 0; j < 4; ++j) acc[I0][j]     = MF(a00, bfr[0][j], acc[I0][j]);     \
        _Pragma("unroll")                                                  \
        for (int j = 0; j < 4; ++j) acc[I0 + 1][j] = MF(a10, bfr[0][j], acc[I0 + 1][j]); \
        _Pragma("unroll")                                                  \
        for (int j = 0; j < 4; ++j) acc[I0][j]     = MF(a01, bfr[1][j], acc[I0][j]);     \
        _Pragma("unroll")                                                  \
        for (int j = 0; j < 4; ++j) acc[I0 + 1][j] = MF(a11, bfr[1][j], acc[I0 + 1][j]); \
        __builtin_amdgcn_s_setprio(0);                                     \
        __builtin_amdgcn_s_barrier();                                      \
    } while (0)

    // prologue: stage tiles 0,1; wait tile0 (8 newest stay in flight)
    G2_STAGE(0, 0);
    G2_STAGE(1, 1);
    asm volatile("s_waitcnt vmcnt(8)" ::: "memory");
    __builtin_amdgcn_s_barrier();

    for (int t = 0; t < G2_NK; ++t) {
        const int cb = (t & 1) * 16384;       // shorts offset of current buffer

        bf16x8 bfr[2][4];
#pragma unroll
        for (int s = 0; s < 2; ++s)
#pragma unroll
            for (int j = 0; j < 4; ++j) bfr[s][j] = LDB(j, s);

        G2_PHASE(0);
        G2_PHASE(2);
        G2_PHASE(4);
        G2_PHASE(6);

        if (t + 2 < G2_NK) {                  // refill the buffer just consumed
            G2_STAGE(t & 1, t + 2);
            asm volatile("s_waitcnt vmcnt(8)" ::: "memory");   // t+1 ready
        } else {
            asm volatile("s_waitcnt vmcnt(0)" ::: "memory");
        }
        __builtin_amdgcn_s_barrier();
    }

#undef G2_PHASE
#undef LDA
#undef LDB
#undef G2_STAGE

    // ---- epilogue: two 128-row halves through LDS (stride 280 shorts) ----
    float bv[4];
#pragma unroll
    for (int j = 0; j < 4; ++j) {
        const int col = n0 + wc * 64 + j * 16 + ml;
        bv[j] = (col < 2047) ? bias[col] : 0.f;
    }
    for (int h = 0; h < 2; ++h) {
        if (wr == h) {
#pragma unroll
            for (int i = 0; i < 8; ++i)
#pragma unroll
                for (int j = 0; j < 4; ++j)
#pragma unroll
                    for (int r = 0; r < 4; ++r) {
                        const float v = acc[i][j][r] + bv[j];
                        lds[(i * 16 + q * 4 + r) * 280 + wc * 64 + j * 16 + ml] = f2bf(v);
                    }
        }
        __syncthreads();
#pragma unroll
        for (int p = 0; p < 8; ++p) {
            const int row  = p * 16 + (tid >> 5);
            const int c8   = (tid & 31) * 8;
            const int grow = m0 + h * 128 + row;
            if (grow < MPAD) {
                *(uint4*)&C[(size_t)grow * G2_N + n0 + c8] =
                    *(const uint4*)&lds[row * 280 + c8];
            }
        }
        __syncthreads();
    }
}

// ---------------- k_gather: one wave per batch row, barrier-free ----------
__global__ __launch_bounds__(64)
void k_gather(const int* __restrict__ lengths, const int* __restrict__ slots,
              const unsigned short* __restrict__ Table, float* __restrict__ out)
{
    const int b    = blockIdx.x;
    const int lane = threadIdx.x;

    float acc[32];
#pragma unroll
    for (int j = 0; j < 32; ++j) acc[j] = 0.f;

    const int len = lengths[b];
    if (len > 0) {
        uint4 u[4];
        {
            const int slot = slots[b * 20];
            const uint4* rp = (const uint4*)(Table + (size_t)slot * 2048);
#pragma unroll
            for (int c = 0; c < 4; ++c) u[c] = rp[c * 64 + lane];
        }
        for (int l = 0; l < len; ++l) {
            uint4 cu[4];
#pragma unroll
            for (int c = 0; c < 4; ++c) cu[c] = u[c];
            if (l + 1 < len) {                       // prefetch next row
                const int ns = slots[b * 20 + l + 1];
                const uint4* rp = (const uint4*)(Table + (size_t)ns * 2048);
#pragma unroll
                for (int c = 0; c < 4; ++c) u[c] = rp[c * 64 + lane];
            }
            float v[32];
#pragma unroll
            for (int c = 0; c < 4; ++c) {
                v[c*8+0] = bf2f(cu[c].x & 0xffffu); v[c*8+1] = bf2f(cu[c].x >> 16);
                v[c*8+2] = bf2f(cu[c].y & 0xffffu); v[c*8+3] = bf2f(cu[c].y >> 16);
                v[c*8+4] = bf2f(cu[c].z & 0xffffu); v[c*8+5] = bf2f(cu[c].z >> 16);
                v[c*8+6] = bf2f(cu[c].w & 0xffffu); v[c*8+7] = bf2f(cu[c].w >> 16);
            }
            float s = 0.f;
#pragma unroll
            for (int j = 0; j < 32; ++j) s += v[j] * v[j];
#pragma unroll
            for (int off = 1; off < 64; off <<= 1) s += __shfl_xor(s, off, 64);
            const float invn = 1.0f / fmaxf(sqrtf(s), 1e-12f);
#pragma unroll
            for (int j = 0; j < 32; ++j) acc[j] += v[j] * invn;
        }
    }

    const size_t base = (size_t)b * 2047;
#pragma unroll
    for (int c = 0; c < 4; ++c) {
        const int col = (c * 64 + lane) * 8;
#pragma unroll
        for (int j = 0; j < 8; ++j)
            if (col + j < 2047) out[base + col + j] = acc[c * 8 + j];
    }
}

// ---------------- launch ----------------

extern "C" void kernel_launch(void* const* d_in, const int* in_sizes, int n_in,
                              void* d_out, int out_size, void* d_ws, size_t ws_size,
                              hipStream_t stream)
{
    const int*   ingrs   = (const int*)d_in[0];
    const int*   lengths = (const int*)d_in[1];
    const float* W1 = (const float*)d_in[2];
    const float* b1 = (const float*)d_in[3];
    const float* W2 = (const float*)d_in[4];
    const float* b2 = (const float*)d_in[5];
    const float* W3 = (const float*)d_in[6];
    const float* b3 = (const float*)d_in[7];
    float* out = (float*)d_out;

    char* ws = (char*)d_ws;
    unsigned short* A1    = (unsigned short*)(ws);
    unsigned short* H2    = (unsigned short*)(ws + 30801920);
    unsigned short* Table = (unsigned short*)(ws + 92405760);
    unsigned short* W2T   = (unsigned short*)(ws + 215613440);
    unsigned short* W3T   = (unsigned short*)(ws + 216662016);
    int*            flags = (int*)(ws + 220856320);
    int*            remap = (int*)(ws + 220976320);
    int*            cnt   = (int*)(ws + 221096320);
    int*            slots = (int*)(ws + 221216448);

    k_mark  <<<(4096 * 20 + 255) / 256, 256, 0, stream>>>(ingrs, lengths, flags, cnt);
    k_assign<<<(VOCAB + 255) / 256, 256, 0, stream>>>(flags, remap, cnt);
    // a1c (15000) | W2T (128)
    k_prep<<<15128, 256, 0, stream>>>(W1, b1, flags, remap, A1, W2, W2T);
    // GEMM1 (1920 swizzled) | W3T transpose (512) | slots (320)
    k_gemm1<<<MT_PAD * 8 + 512 + 320, 256, 0, stream>>>(
        A1, W2T, b2, H2, cnt, W3, W3T, ingrs, lengths, remap, slots);
    // GEMM2 (256^2 8-wave dbuf): Table = H2 @ W3 + b3
    k_gemm2<<<G2_MT * 8, 512, 0, stream>>>(H2, W3T, b3, Table, cnt);

    k_gather<<<4096, 64, 0, stream>>>(lengths, slots, Table, out);
}

// Round 3
// 311.171 us; speedup vs baseline: 1.0552x; 1.0299x over previous
//
#include <hip/hip_runtime.h>

#define VOCAB 30000
#define MPAD  30080   // 235 * 128
#define MT_PAD 240    // m-tiles padded to multiple of 8 (XCD count)

typedef __attribute__((ext_vector_type(8))) short bf16x8;
typedef __attribute__((ext_vector_type(4))) float f32x4;

__device__ __forceinline__ unsigned short f2bf(float f) {
    unsigned int u = __builtin_bit_cast(unsigned int, f);
    u += 0x7fffu + ((u >> 16) & 1u);          // round-to-nearest-even
    return (unsigned short)(u >> 16);
}
__device__ __forceinline__ float bf2f(unsigned int h) {
    unsigned int u = h << 16;
    return __builtin_bit_cast(float, u);
}

__device__ __forceinline__ void async16(const void* g, void* l) {
    __builtin_amdgcn_global_load_lds(
        (__attribute__((address_space(1))) void*)g,
        (__attribute__((address_space(3))) void*)l, 16, 0, 0);
}

// ---------------- compaction ----------------
// flags relies on the harness's 0xAA ws poison: "marked" == exactly 1.
__global__ void k_mark(const int* __restrict__ ingrs, const int* __restrict__ lengths,
                       int* __restrict__ flags, int* __restrict__ cnt)
{
    const int i = blockIdx.x * 256 + threadIdx.x;
    if (i == 0) *cnt = 0;
    if (i >= 4096 * 20) return;
    const int b = i / 20;
    const int l = i - b * 20;
    if (l < lengths[b]) flags[ingrs[i]] = 1;
}

__global__ void k_assign(const int* __restrict__ flags, int* __restrict__ remap,
                         int* __restrict__ cnt)
{
    const int i = blockIdx.x * 256 + threadIdx.x;
    if (i < VOCAB && flags[i] == 1) remap[i] = atomicAdd(cnt, 1);
}

// ---------------- shared device bodies ----------------

__device__ __forceinline__ void transpose_body(
    const float* __restrict__ in, unsigned short* __restrict__ out,
    int K, int Nin, int n0, int k0, int tid, float (*t)[65])
{
#pragma unroll
    for (int p = 0; p < 16; ++p) {
        const int lin = p * 256 + tid;
        const int kk = lin >> 6, nn = lin & 63;
        const int n = n0 + nn;
        t[kk][nn] = (n < Nin) ? in[(size_t)(k0 + kk) * Nin + n] : 0.f;
    }
    __syncthreads();
#pragma unroll
    for (int p = 0; p < 16; ++p) {
        const int lin = p * 256 + tid;
        const int nn = lin >> 6, kk = lin & 63;
        out[(size_t)(n0 + nn) * K + k0 + kk] = f2bf(t[kk][nn]);
    }
}

// m97-style BK=64 XOR-swizzled MFMA GEMM tile; id pre-swizzled by caller.
// (kept for GEMM1)
__device__ __forceinline__ void gemm_body(
    unsigned short* smem,
    const unsigned short* __restrict__ A, const unsigned short* __restrict__ BT,
    const float* __restrict__ bias, int bias_n, unsigned short* __restrict__ C,
    int K, int N, int relu, int mc, int id, int nt_shift)
{
    const int w  = id >> 3;
    const int n_tile = w & ((1 << nt_shift) - 1);
    const int m_tile = (id & 7) + ((w >> nt_shift) << 3);
    const int m0 = m_tile * 128;
    if (m0 >= mc) return;
    const int n0 = n_tile * 128;

    unsigned short* As = smem;
    unsigned short* Bs = smem + 8192;

    const int tid  = threadIdx.x;
    const int lane = tid & 63;
    const int wid  = tid >> 6;
    const int wr   = wid >> 1;
    const int wc   = wid & 1;
    const int q  = lane >> 4;
    const int ml = lane & 15;

    f32x4 acc[4][4];
    const f32x4 zero = {0.f, 0.f, 0.f, 0.f};
#pragma unroll
    for (int i = 0; i < 4; ++i)
#pragma unroll
        for (int j = 0; j < 4; ++j) acc[i][j] = zero;

    const int rg = lane >> 3;
    const int kc = (lane & 7) ^ rg;
    const unsigned short* pA = A  + (size_t)(m0 + wid * 32 + rg) * K + kc * 8;
    const unsigned short* pB = BT + (size_t)(n0 + wid * 32 + rg) * K + kc * 8;
    unsigned short* lA = &As[wid * 4 * 512 + lane * 8];
    unsigned short* lB = &Bs[wid * 4 * 512 + lane * 8];

    const int swz0 = (q ^ (ml & 7)) * 8;

    for (int k0 = 0; k0 < K; k0 += 64) {
#pragma unroll
        for (int gg = 0; gg < 4; ++gg) {
            async16(pA + (size_t)gg * 8 * K, lA + gg * 512);
            async16(pB + (size_t)gg * 8 * K, lB + gg * 512);
        }
        pA += 64; pB += 64;
        __syncthreads();

        bf16x8 af[4], bfr[4];
#pragma unroll
        for (int t = 0; t < 4; ++t) {
            af[t]  = *(const bf16x8*)&As[(wr * 64 + t * 16 + ml) * 64 + swz0];
            bfr[t] = *(const bf16x8*)&Bs[(wc * 64 + t * 16 + ml) * 64 + swz0];
        }
#pragma unroll
        for (int i = 0; i < 4; ++i)
#pragma unroll
            for (int j = 0; j < 4; ++j)
                acc[i][j] = __builtin_amdgcn_mfma_f32_16x16x32_bf16(
                    af[i], bfr[j], acc[i][j], 0, 0, 0);
#pragma unroll
        for (int t = 0; t < 4; ++t) {
            af[t]  = *(const bf16x8*)&As[(wr * 64 + t * 16 + ml) * 64 + (swz0 ^ 32)];
            bfr[t] = *(const bf16x8*)&Bs[(wc * 64 + t * 16 + ml) * 64 + (swz0 ^ 32)];
        }
#pragma unroll
        for (int i = 0; i < 4; ++i)
#pragma unroll
            for (int j = 0; j < 4; ++j)
                acc[i][j] = __builtin_amdgcn_mfma_f32_16x16x32_bf16(
                    af[i], bfr[j], acc[i][j], 0, 0, 0);

        __syncthreads();
    }

    // epilogue phase 1: bias/relu/round into LDS (stride 136 shorts)
#pragma unroll
    for (int i = 0; i < 4; ++i) {
#pragma unroll
        for (int j = 0; j < 4; ++j) {
#pragma unroll
            for (int r = 0; r < 4; ++r) {
                const int rl = wr * 64 + i * 16 + q * 4 + r;
                const int cl = wc * 64 + j * 16 + ml;
                float v = acc[i][j][r];
                const int col = n0 + cl;
                v += (col < bias_n) ? bias[col] : 0.f;
                if (relu) v = fmaxf(v, 0.f);
                smem[rl * 136 + cl] = f2bf(v);
            }
        }
    }
    __syncthreads();
#pragma unroll
    for (int p = 0; p < 8; ++p) {
        const int rr = p * 16 + (tid >> 4);
        const int cc = tid & 15;
        const uint4 val = *(const uint4*)&smem[rr * 136 + cc * 8];
        *(uint4*)&C[(size_t)(m0 + rr) * N + n0 + cc * 8] = val;
    }
}

// ---------------- k_prep: A1 gather-activate | W2 transpose ----------------
__global__ __launch_bounds__(256)
void k_prep(const float* __restrict__ W1, const float* __restrict__ b1,
            const int* __restrict__ flags, const int* __restrict__ remap,
            unsigned short* __restrict__ A1,
            const float* __restrict__ W2, unsigned short* __restrict__ W2T)
{
    __shared__ float t[64][65];
    const int bid = blockIdx.x;
    const int tid = threadIdx.x;

    if (bid < 15000) {                       // 2 vocab rows per block
        const int id = bid * 2 + (tid >> 7);
        if (flags[id] != 1) return;
        const int row = remap[id];
        const int k4  = (tid & 127) * 4;
        const float4 w  = *(const float4*)(W1 + (size_t)id * 512 + k4);
        const float4 bb = *(const float4*)(b1 + k4);
        unsigned short o[4];
        o[0] = f2bf(fmaxf(w.x + bb.x, 0.f));
        o[1] = f2bf(fmaxf(w.y + bb.y, 0.f));
        o[2] = f2bf(fmaxf(w.z + bb.z, 0.f));
        o[3] = f2bf(fmaxf(w.w + bb.w, 0.f));
        *(uint2*)(A1 + (size_t)row * 512 + k4) = *(const uint2*)o;
    } else {                                 // W2 [512x1024] -> W2T [1024x512]
        const int local = bid - 15000;
        transpose_body(W2, W2T, 512, 1024, (local & 15) * 64, (local >> 4) * 64, tid, t);
    }
}

// ---------------- k_gemm1: GEMM1 + piggybacked W3 transpose + slots --------
__global__ __launch_bounds__(256)
void k_gemm1(const unsigned short* __restrict__ A1, const unsigned short* __restrict__ W2T,
             const float* __restrict__ b2, unsigned short* __restrict__ H2,
             const int* __restrict__ cnt,
             const float* __restrict__ W3, unsigned short* __restrict__ W3T,
             const int* __restrict__ ingrs, const int* __restrict__ lengths,
             const int* __restrict__ remap, int* __restrict__ slots)
{
    __shared__ __align__(16) unsigned short smem[128 * 136];
    const int bid = blockIdx.x;
    if (bid < MT_PAD * 8) {                  // GEMM1: H2 = relu(A1 @ W2 + b2)
        const int mc = (*cnt + 127) & ~127;
        gemm_body(smem, A1, W2T, b2, 1024, H2, 512, 1024, 1, mc, bid, 3);
    } else if (bid < MT_PAD * 8 + 512) {     // W3 [1024x2047] -> W3T [2048x1024]
        const int local = bid - MT_PAD * 8;
        transpose_body(W3, W3T, 1024, 2047, (local & 31) * 64, (local >> 5) * 64,
                       threadIdx.x, (float(*)[65])smem);
    } else {                                 // slots[b,l] = remap[ingrs[b,l]]
        const int i = (bid - (MT_PAD * 8 + 512)) * 256 + threadIdx.x;
        if (i < 4096 * 20) {
            const int b = i / 20;
            const int l = i - b * 20;
            if (l < lengths[b]) slots[i] = remap[ingrs[i]];
        }
    }
}

// ---------------- k_gemm2: 256x256, 8 waves, 4-phase/K-tile template -------
// m201-style schedule: per K-tile 4 phases of
//   {ds_read (4-8 x b128) ; stage one half-tile unit (2 x global_load_lds);
//    s_barrier; lgkmcnt(0)+sched_barrier; setprio(1); 16 MFMA; setprio(0);
//    s_barrier}
// Stage units recycle LDS half-regions whose last reader finished >=1 phase
// earlier:  ph_d(t): A0,B0 of t+2 -> buf(t&1);  ph_a(t): A1 of t+1;
// ph_b(t): B1 of t+1 -> buf(~t&1).  vmcnt(4) once per K-tile at ph_d keeps
// t+2's A0/B0 in flight (never drains to 0 until the end).
#define G2_NK 16      // K=1024 / BK=64
#define G2_K  1024
#define G2_N  2048
#define G2_MT 120     // padded m-tiles (multiple of 8 XCDs); active: ceil(mc/256)

#define MF(a, b, c) __builtin_amdgcn_mfma_f32_16x16x32_bf16(a, b, c, 0, 0, 0)

__global__ __launch_bounds__(512, 2)
void k_gemm2(const unsigned short* __restrict__ A, const unsigned short* __restrict__ BT,
             const float* __restrict__ bias, unsigned short* __restrict__ C,
             const int* __restrict__ cnt)
{
    __shared__ __align__(16) unsigned short lds[65536];   // 128 KiB: A/B x dbuf

    const int id = blockIdx.x;
    const int w  = id >> 3;
    const int n_tile = w & 7;                 // N=2048 -> 8 n-tiles
    const int m_tile = (id & 7) + ((w >> 3) << 3);  // XCD-banded m
    const int m0 = m_tile * 256;
    const int mc = (*cnt + 255) & ~255;
    if (m0 >= mc) return;
    const int n0 = n_tile * 256;

    const int tid  = threadIdx.x;
    const int lane = tid & 63;
    const int w0   = tid >> 6;                // wave 0..7
    const int wr   = w0 >> 2;                 // 0..1  (128-row half)
    const int wc   = w0 & 3;                  // 0..3  (64-col strip)
    const int q    = lane >> 4;
    const int ml   = lane & 15;
    const int m7   = ml & 7;

    f32x4 acc[8][4];
    const f32x4 zero = {0.f, 0.f, 0.f, 0.f};
#pragma unroll
    for (int i = 0; i < 8; ++i)
#pragma unroll
        for (int j = 0; j < 4; ++j) acc[i][j] = zero;

    // staging: each wave covers rows [w0*16, w0*16+16) of EVERY 128-row half
    // (2 async16 per half-tile unit per wave -- template constant).
    // global source pre-swizzled: logical chunk (lane&7)^rg lands at phys lane&7,
    // matching the read-side XOR with (row&7)=rg.
    const int rg = lane >> 3;
    const int kc = (lane & 7) ^ rg;
    const unsigned short* gA = A  + (size_t)(m0 + w0 * 16 + rg) * G2_K + kc * 8;
    const unsigned short* gB = BT + (size_t)(n0 + w0 * 16 + rg) * G2_K + kc * 8;
    const int dst0 = (w0 * 16) * 64 + lane * 8;   // shorts within a region

    // one half-tile unit: AB 0=A 1=B, H half (0/1), B_ dbuf, T k-tile
#define G2_U(AB, H, B_, T) do {                                                \
        const unsigned short* _s = ((AB) ? gB : gA)                            \
            + (size_t)((H) * 128) * G2_K + (size_t)(T) * 64;                   \
        unsigned short* _d = &lds[(AB) * 32768 + (B_) * 16384                  \
            + ((H) * 128) * 64 + dst0];                                        \
        async16(_s, _d);                                                       \
        async16(_s + (size_t)8 * G2_K, _d + 8 * 64);                           \
    } while (0)

    // fragment reads: logical chunk (S*4+q), physical = logical ^ (row&7)=^m7
#define LDA(I, S) (*(const bf16x8*)&lds[cb + ((wr * 128 + (I) * 16 + ml) * 64) + ((((S) * 4 + q) ^ m7) * 8)])
#define LDB(J, S) (*(const bf16x8*)&lds[32768 + cb + ((wc * 64 + (J) * 16 + ml) * 64) + ((((S) * 4 + q) ^ m7) * 8)])

#define G2_MFMA16(AI0, BF)                                                     \
        _Pragma("unroll")                                                      \
        for (int i = 0; i < 4; ++i)                                            \
        _Pragma("unroll")                                                      \
        for (int j = 0; j < 4; ++j)                                            \
            acc[(AI0) + i][j] = MF(afr[i], BF[j], acc[(AI0) + i][j]);

#define G2_BAR()  __builtin_amdgcn_s_barrier()
#define G2_LGKM() do { asm volatile("s_waitcnt lgkmcnt(0)" ::: "memory");      \
                       __builtin_amdgcn_sched_barrier(0); } while (0)

    // prologue: tile0 fully, tile1 A0+B0; wait tile0 (4 newest stay in flight)
    G2_U(0, 0, 0, 0); G2_U(0, 1, 0, 0); G2_U(1, 0, 0, 0); G2_U(1, 1, 0, 0);
    G2_U(0, 0, 1, 1); G2_U(1, 0, 1, 1);
    asm volatile("s_waitcnt vmcnt(4)" ::: "memory");
    G2_BAR();

    for (int t = 0; t < G2_NK; ++t) {
        const int cb  = (t & 1) * 16384;
        const int cur = t & 1, nxt = cur ^ 1;
        bf16x8 afr[4], bS0[4], bS1[4];

        // ---- ph_a: slice0, m-half0; stage A1 of t+1 ----
#pragma unroll
        for (int j = 0; j < 4; ++j) bS0[j] = LDB(j, 0);
#pragma unroll
        for (int i = 0; i < 4; ++i) afr[i] = LDA(i, 0);
        if (t + 1 < G2_NK) G2_U(0, 1, nxt, t + 1);
        G2_BAR(); G2_LGKM();
        __builtin_amdgcn_s_setprio(1);
        G2_MFMA16(0, bS0)
        __builtin_amdgcn_s_setprio(0);
        G2_BAR();

        // ---- ph_b: slice0, m-half1; stage B1 of t+1 ----
#pragma unroll
        for (int i = 0; i < 4; ++i) afr[i] = LDA(4 + i, 0);
        if (t + 1 < G2_NK) G2_U(1, 1, nxt, t + 1);
        G2_BAR(); G2_LGKM();
        __builtin_amdgcn_s_setprio(1);
        G2_MFMA16(4, bS0)
        __builtin_amdgcn_s_setprio(0);
        G2_BAR();

        // ---- ph_c: slice1, m-half0 ----
#pragma unroll
        for (int j = 0; j < 4; ++j) bS1[j] = LDB(j, 1);
#pragma unroll
        for (int i = 0; i < 4; ++i) afr[i] = LDA(i, 1);
        G2_BAR(); G2_LGKM();
        __builtin_amdgcn_s_setprio(1);
        G2_MFMA16(0, bS1)
        __builtin_amdgcn_s_setprio(0);
        G2_BAR();

        // ---- ph_d: slice1, m-half1; stage A0,B0 of t+2; counted vmcnt ----
#pragma unroll
        for (int i = 0; i < 4; ++i) afr[i] = LDA(4 + i, 1);
        if (t + 2 < G2_NK) { G2_U(0, 0, cur, t + 2); G2_U(1, 0, cur, t + 2); }
        G2_BAR(); G2_LGKM();
        __builtin_amdgcn_s_setprio(1);
        G2_MFMA16(4, bS1)
        __builtin_amdgcn_s_setprio(0);
        if (t + 2 < G2_NK) asm volatile("s_waitcnt vmcnt(4)" ::: "memory");
        else               asm volatile("s_waitcnt vmcnt(0)" ::: "memory");
        G2_BAR();
    }

#undef G2_U
#undef LDA
#undef LDB
#undef G2_MFMA16
#undef G2_BAR
#undef G2_LGKM

    // ---- epilogue: two 128-row halves through LDS (stride 280 shorts) ----
    float bv[4];
#pragma unroll
    for (int j = 0; j < 4; ++j) {
        const int col = n0 + wc * 64 + j * 16 + ml;
        bv[j] = (col < 2047) ? bias[col] : 0.f;
    }
    for (int h = 0; h < 2; ++h) {
        if (wr == h) {
#pragma unroll
            for (int i = 0; i < 8; ++i)
#pragma unroll
                for (int j = 0; j < 4; ++j)
#pragma unroll
                    for (int r = 0; r < 4; ++r) {
                        const float v = acc[i][j][r] + bv[j];
                        lds[(i * 16 + q * 4 + r) * 280 + wc * 64 + j * 16 + ml] = f2bf(v);
                    }
        }
        __syncthreads();
#pragma unroll
        for (int p = 0; p < 8; ++p) {
            const int row  = p * 16 + (tid >> 5);
            const int c8   = (tid & 31) * 8;
            const int grow = m0 + h * 128 + row;
            if (grow < MPAD) {
                *(uint4*)&C[(size_t)grow * G2_N + n0 + c8] =
                    *(const uint4*)&lds[row * 280 + c8];
            }
        }
        __syncthreads();
    }
}

// ---------------- k_gather: one wave per batch row, barrier-free ----------
__global__ __launch_bounds__(64)
void k_gather(const int* __restrict__ lengths, const int* __restrict__ slots,
              const unsigned short* __restrict__ Table, float* __restrict__ out)
{
    const int b    = blockIdx.x;
    const int lane = threadIdx.x;

    float acc[32];
#pragma unroll
    for (int j = 0; j < 32; ++j) acc[j] = 0.f;

    const int len = lengths[b];
    if (len > 0) {
        uint4 u[4];
        {
            const int slot = slots[b * 20];
            const uint4* rp = (const uint4*)(Table + (size_t)slot * 2048);
#pragma unroll
            for (int c = 0; c < 4; ++c) u[c] = rp[c * 64 + lane];
        }
        for (int l = 0; l < len; ++l) {
            uint4 cu[4];
#pragma unroll
            for (int c = 0; c < 4; ++c) cu[c] = u[c];
            if (l + 1 < len) {                       // prefetch next row
                const int ns = slots[b * 20 + l + 1];
                const uint4* rp = (const uint4*)(Table + (size_t)ns * 2048);
#pragma unroll
                for (int c = 0; c < 4; ++c) u[c] = rp[c * 64 + lane];
            }
            float v[32];
#pragma unroll
            for (int c = 0; c < 4; ++c) {
                v[c*8+0] = bf2f(cu[c].x & 0xffffu); v[c*8+1] = bf2f(cu[c].x >> 16);
                v[c*8+2] = bf2f(cu[c].y & 0xffffu); v[c*8+3] = bf2f(cu[c].y >> 16);
                v[c*8+4] = bf2f(cu[c].z & 0xffffu); v[c*8+5] = bf2f(cu[c].z >> 16);
                v[c*8+6] = bf2f(cu[c].w & 0xffffu); v[c*8+7] = bf2f(cu[c].w >> 16);
            }
            float s = 0.f;
#pragma unroll
            for (int j = 0; j < 32; ++j) s += v[j] * v[j];
#pragma unroll
            for (int off = 1; off < 64; off <<= 1) s += __shfl_xor(s, off, 64);
            const float invn = 1.0f / fmaxf(sqrtf(s), 1e-12f);
#pragma unroll
            for (int j = 0; j < 32; ++j) acc[j] += v[j] * invn;
        }
    }

    const size_t base = (size_t)b * 2047;
#pragma unroll
    for (int c = 0; c < 4; ++c) {
        const int col = (c * 64 + lane) * 8;
#pragma unroll
        for (int j = 0; j < 8; ++j)
            if (col + j < 2047) out[base + col + j] = acc[c * 8 + j];
    }
}

// ---------------- launch ----------------

extern "C" void kernel_launch(void* const* d_in, const int* in_sizes, int n_in,
                              void* d_out, int out_size, void* d_ws, size_t ws_size,
                              hipStream_t stream)
{
    const int*   ingrs   = (const int*)d_in[0];
    const int*   lengths = (const int*)d_in[1];
    const float* W1 = (const float*)d_in[2];
    const float* b1 = (const float*)d_in[3];
    const float* W2 = (const float*)d_in[4];
    const float* b2 = (const float*)d_in[5];
    const float* W3 = (const float*)d_in[6];
    const float* b3 = (const float*)d_in[7];
    float* out = (float*)d_out;

    char* ws = (char*)d_ws;
    unsigned short* A1    = (unsigned short*)(ws);
    unsigned short* H2    = (unsigned short*)(ws + 30801920);
    unsigned short* Table = (unsigned short*)(ws + 92405760);
    unsigned short* W2T   = (unsigned short*)(ws + 215613440);
    unsigned short* W3T   = (unsigned short*)(ws + 216662016);
    int*            flags = (int*)(ws + 220856320);
    int*            remap = (int*)(ws + 220976320);
    int*            cnt   = (int*)(ws + 221096320);
    int*            slots = (int*)(ws + 221216448);

    k_mark  <<<(4096 * 20 + 255) / 256, 256, 0, stream>>>(ingrs, lengths, flags, cnt);
    k_assign<<<(VOCAB + 255) / 256, 256, 0, stream>>>(flags, remap, cnt);
    // a1c (15000) | W2T (128)
    k_prep<<<15128, 256, 0, stream>>>(W1, b1, flags, remap, A1, W2, W2T);
    // GEMM1 (1920 swizzled) | W3T transpose (512) | slots (320)
    k_gemm1<<<MT_PAD * 8 + 512 + 320, 256, 0, stream>>>(
        A1, W2T, b2, H2, cnt, W3, W3T, ingrs, lengths, remap, slots);
    // GEMM2 (256^2 8-wave, 4-phase template): Table = H2 @ W3 + b3
    k_gemm2<<<G2_MT * 8, 512, 0, stream>>>(H2, W3T, b3, Table, cnt);

    k_gather<<<4096, 64, 0, stream>>>(lengths, slots, Table, out);
}

// Round 4
// 309.266 us; speedup vs baseline: 1.0617x; 1.0062x over previous
//
#include <hip/hip_runtime.h>

#define VOCAB 30000
#define MPAD  30080   // 235 * 128
#define G_MT  120     // 256-row m-tiles padded to multiple of 8 (XCD count)

typedef __attribute__((ext_vector_type(8))) short bf16x8;
typedef __attribute__((ext_vector_type(4))) float f32x4;

__device__ __forceinline__ unsigned short f2bf(float f) {
    unsigned int u = __builtin_bit_cast(unsigned int, f);
    u += 0x7fffu + ((u >> 16) & 1u);          // round-to-nearest-even
    return (unsigned short)(u >> 16);
}
__device__ __forceinline__ float bf2f(unsigned int h) {
    unsigned int u = h << 16;
    return __builtin_bit_cast(float, u);
}

__device__ __forceinline__ void async16(const void* g, void* l) {
    __builtin_amdgcn_global_load_lds(
        (__attribute__((address_space(1))) void*)g,
        (__attribute__((address_space(3))) void*)l, 16, 0, 0);
}

// ---------------- compaction ----------------
// flags relies on the harness's 0xAA ws poison: "marked" == exactly 1.
__global__ void k_mark(const int* __restrict__ ingrs, const int* __restrict__ lengths,
                       int* __restrict__ flags, int* __restrict__ cnt)
{
    const int i = blockIdx.x * 256 + threadIdx.x;
    if (i == 0) *cnt = 0;
    if (i >= 4096 * 20) return;
    const int b = i / 20;
    const int l = i - b * 20;
    if (l < lengths[b]) flags[ingrs[i]] = 1;
}

__global__ void k_assign(const int* __restrict__ flags, int* __restrict__ remap,
                         int* __restrict__ cnt)
{
    const int i = blockIdx.x * 256 + threadIdx.x;
    if (i < VOCAB && flags[i] == 1) remap[i] = atomicAdd(cnt, 1);
}

// ---------------- transpose helper ----------------
__device__ __forceinline__ void transpose_body(
    const float* __restrict__ in, unsigned short* __restrict__ out,
    int K, int Nin, int n0, int k0, int tid, float (*t)[65])
{
#pragma unroll
    for (int p = 0; p < 16; ++p) {
        const int lin = p * 256 + tid;
        const int kk = lin >> 6, nn = lin & 63;
        const int n = n0 + nn;
        t[kk][nn] = (n < Nin) ? in[(size_t)(k0 + kk) * Nin + n] : 0.f;
    }
    __syncthreads();
#pragma unroll
    for (int p = 0; p < 16; ++p) {
        const int lin = p * 256 + tid;
        const int nn = lin >> 6, kk = lin & 63;
        out[(size_t)(n0 + nn) * K + k0 + kk] = f2bf(t[kk][nn]);
    }
}

// ---------------- unified 256x256 8-wave 4-phase GEMM body ----------------
// Per K-tile: 4 phases of {ds_read subtile; stage one half-tile unit
// (2 x global_load_lds); s_barrier; lgkmcnt(0)+sched_barrier; setprio(1);
// 16 MFMA; setprio(0); s_barrier}.  Stage units recycle LDS half-regions
// whose last reader finished >=1 phase earlier; per-tile wait is vmcnt(4)
// (never 0 until the drain).  Verified on k_gemm2 in rounds 2-3.
#define MF(a, b, c) __builtin_amdgcn_mfma_f32_16x16x32_bf16(a, b, c, 0, 0, 0)

#define G_U(AB, H, B_, T) do {                                                 \
        const unsigned short* _s = ((AB) ? gB : gA)                            \
            + (size_t)((H) * 128) * K + (size_t)(T) * 64;                      \
        unsigned short* _d = &lds[(AB) * 32768 + (B_) * 16384                  \
            + ((H) * 128) * 64 + dst0];                                        \
        async16(_s, _d);                                                       \
        async16(_s + (size_t)8 * K, _d + 8 * 64);                              \
    } while (0)

#define LDA(I, S) (*(const bf16x8*)&lds[cb + ((wr * 128 + (I) * 16 + ml) * 64) + ((((S) * 4 + q) ^ m7) * 8)])
#define LDB(J, S) (*(const bf16x8*)&lds[32768 + cb + ((wc * 64 + (J) * 16 + ml) * 64) + ((((S) * 4 + q) ^ m7) * 8)])

#define G_MFMA16(AI0, BF)                                                      \
        _Pragma("unroll")                                                      \
        for (int i = 0; i < 4; ++i)                                            \
        _Pragma("unroll")                                                      \
        for (int j = 0; j < 4; ++j)                                            \
            acc[(AI0) + i][j] = MF(afr[i], BF[j], acc[(AI0) + i][j]);

#define G_BAR()  __builtin_amdgcn_s_barrier()
#define G_LGKM() do { asm volatile("s_waitcnt lgkmcnt(0)" ::: "memory");       \
                      __builtin_amdgcn_sched_barrier(0); } while (0)

__device__ __forceinline__ void gemm256_body(
    unsigned short* lds,
    const unsigned short* __restrict__ A, const unsigned short* __restrict__ BT,
    const float* __restrict__ bias, int bias_n, unsigned short* __restrict__ C,
    int K, int NK, int N, int relu, int mc, int id, int nt_shift)
{
    const int w  = id >> 3;
    const int n_tile = w & ((1 << nt_shift) - 1);
    const int m_tile = (id & 7) + ((w >> nt_shift) << 3);  // XCD-banded m
    const int m0 = m_tile * 256;
    if (m0 >= mc) return;
    const int n0 = n_tile * 256;

    const int tid  = threadIdx.x;
    const int lane = tid & 63;
    const int w0   = tid >> 6;                // wave 0..7
    const int wr   = w0 >> 2;                 // 0..1  (128-row half)
    const int wc   = w0 & 3;                  // 0..3  (64-col strip)
    const int q    = lane >> 4;
    const int ml   = lane & 15;
    const int m7   = ml & 7;

    f32x4 acc[8][4];
    const f32x4 zero = {0.f, 0.f, 0.f, 0.f};
#pragma unroll
    for (int i = 0; i < 8; ++i)
#pragma unroll
        for (int j = 0; j < 4; ++j) acc[i][j] = zero;

    // staging: each wave covers rows [w0*16, w0*16+16) of every 128-row half;
    // global source pre-swizzled so read-side XOR with (row&7) sees linear k.
    const int rg = lane >> 3;
    const int kc = (lane & 7) ^ rg;
    const unsigned short* gA = A  + (size_t)(m0 + w0 * 16 + rg) * K + kc * 8;
    const unsigned short* gB = BT + (size_t)(n0 + w0 * 16 + rg) * K + kc * 8;
    const int dst0 = (w0 * 16) * 64 + lane * 8;

    // prologue: tile0 fully, tile1 A0+B0; vmcnt(4) leaves t1's units in flight
    G_U(0, 0, 0, 0); G_U(0, 1, 0, 0); G_U(1, 0, 0, 0); G_U(1, 1, 0, 0);
    G_U(0, 0, 1, 1); G_U(1, 0, 1, 1);
    asm volatile("s_waitcnt vmcnt(4)" ::: "memory");
    G_BAR();

    for (int t = 0; t < NK; ++t) {
        const int cb  = (t & 1) * 16384;
        const int nxt = (t & 1) ^ 1;
        bf16x8 afr[4], bS0[4], bS1[4];

        // ---- ph_a: slice0, m-half0; stage A1 of t+1 ----
#pragma unroll
        for (int j = 0; j < 4; ++j) bS0[j] = LDB(j, 0);
#pragma unroll
        for (int i = 0; i < 4; ++i) afr[i] = LDA(i, 0);
        if (t + 1 < NK) G_U(0, 1, nxt, t + 1);
        G_BAR(); G_LGKM();
        __builtin_amdgcn_s_setprio(1);
        G_MFMA16(0, bS0)
        __builtin_amdgcn_s_setprio(0);
        G_BAR();

        // ---- ph_b: slice0, m-half1; stage B1 of t+1 ----
#pragma unroll
        for (int i = 0; i < 4; ++i) afr[i] = LDA(4 + i, 0);
        if (t + 1 < NK) G_U(1, 1, nxt, t + 1);
        G_BAR(); G_LGKM();
        __builtin_amdgcn_s_setprio(1);
        G_MFMA16(4, bS0)
        __builtin_amdgcn_s_setprio(0);
        G_BAR();

        // ---- ph_c: slice1, m-half0 ----
#pragma unroll
        for (int j = 0; j < 4; ++j) bS1[j] = LDB(j, 1);
#pragma unroll
        for (int i = 0; i < 4; ++i) afr[i] = LDA(i, 1);
        G_BAR(); G_LGKM();
        __builtin_amdgcn_s_setprio(1);
        G_MFMA16(0, bS1)
        __builtin_amdgcn_s_setprio(0);
        G_BAR();

        // ---- ph_d: slice1, m-half1; stage A0,B0 of t+2; counted vmcnt ----
#pragma unroll
        for (int i = 0; i < 4; ++i) afr[i] = LDA(4 + i, 1);
        if (t + 2 < NK) { G_U(0, 0, t & 1, t + 2); G_U(1, 0, t & 1, t + 2); }
        G_BAR(); G_LGKM();
        __builtin_amdgcn_s_setprio(1);
        G_MFMA16(4, bS1)
        __builtin_amdgcn_s_setprio(0);
        if (t + 2 < NK) asm volatile("s_waitcnt vmcnt(4)" ::: "memory");
        else            asm volatile("s_waitcnt vmcnt(0)" ::: "memory");
        G_BAR();
    }

    // ---- epilogue: two 128-row halves through LDS (stride 280 shorts) ----
    float bv[4];
#pragma unroll
    for (int j = 0; j < 4; ++j) {
        const int col = n0 + wc * 64 + j * 16 + ml;
        bv[j] = (col < bias_n) ? bias[col] : 0.f;
    }
    for (int h = 0; h < 2; ++h) {
        if (wr == h) {
#pragma unroll
            for (int i = 0; i < 8; ++i)
#pragma unroll
                for (int j = 0; j < 4; ++j)
#pragma unroll
                    for (int r = 0; r < 4; ++r) {
                        float v = acc[i][j][r] + bv[j];
                        if (relu) v = fmaxf(v, 0.f);
                        lds[(i * 16 + q * 4 + r) * 280 + wc * 64 + j * 16 + ml] = f2bf(v);
                    }
        }
        __syncthreads();
#pragma unroll
        for (int p = 0; p < 8; ++p) {
            const int row  = p * 16 + (tid >> 5);
            const int c8   = (tid & 31) * 8;
            const int grow = m0 + h * 128 + row;
            if (grow < MPAD) {
                *(uint4*)&C[(size_t)grow * N + n0 + c8] =
                    *(const uint4*)&lds[row * 280 + c8];
            }
        }
        __syncthreads();
    }
}

// ---------------- k_prep: A1 gather-activate | W2T | W3T | slots ----------
__global__ __launch_bounds__(256)
void k_prep(const float* __restrict__ W1, const float* __restrict__ b1,
            const int* __restrict__ flags, const int* __restrict__ remap,
            unsigned short* __restrict__ A1,
            const float* __restrict__ W2, unsigned short* __restrict__ W2T,
            const float* __restrict__ W3, unsigned short* __restrict__ W3T,
            const int* __restrict__ ingrs, const int* __restrict__ lengths,
            int* __restrict__ slots)
{
    __shared__ float t[64][65];
    const int bid = blockIdx.x;
    const int tid = threadIdx.x;

    if (bid < 15000) {                       // 2 vocab rows per block
        const int id = bid * 2 + (tid >> 7);
        if (flags[id] != 1) return;
        const int row = remap[id];
        const int k4  = (tid & 127) * 4;
        const float4 w  = *(const float4*)(W1 + (size_t)id * 512 + k4);
        const float4 bb = *(const float4*)(b1 + k4);
        unsigned short o[4];
        o[0] = f2bf(fmaxf(w.x + bb.x, 0.f));
        o[1] = f2bf(fmaxf(w.y + bb.y, 0.f));
        o[2] = f2bf(fmaxf(w.z + bb.z, 0.f));
        o[3] = f2bf(fmaxf(w.w + bb.w, 0.f));
        *(uint2*)(A1 + (size_t)row * 512 + k4) = *(const uint2*)o;
    } else if (bid < 15128) {                // W2 [512x1024] -> W2T [1024x512]
        const int local = bid - 15000;
        transpose_body(W2, W2T, 512, 1024, (local & 15) * 64, (local >> 4) * 64, tid, t);
    } else if (bid < 15640) {                // W3 [1024x2047] -> W3T [2048x1024]
        const int local = bid - 15128;
        transpose_body(W3, W3T, 1024, 2047, (local & 31) * 64, (local >> 5) * 64, tid, t);
    } else {                                 // slots[b,l] = remap[ingrs[b,l]]
        const int i = (bid - 15640) * 256 + tid;
        if (i < 4096 * 20) {
            const int b = i / 20;
            const int l = i - b * 20;
            if (l < lengths[b]) slots[i] = remap[ingrs[i]];
        }
    }
}

// ---------------- GEMM kernels (unified body) ----------------
__global__ __launch_bounds__(512, 2)
void k_gemm1(const unsigned short* __restrict__ A1, const unsigned short* __restrict__ W2T,
             const float* __restrict__ b2, unsigned short* __restrict__ H2,
             const int* __restrict__ cnt)
{
    __shared__ __align__(16) unsigned short lds[65536];
    const int mc = (*cnt + 255) & ~255;
    gemm256_body(lds, A1, W2T, b2, 1024, H2, 512, 8, 1024, 1, mc, blockIdx.x, 2);
}

__global__ __launch_bounds__(512, 2)
void k_gemm2(const unsigned short* __restrict__ H2, const unsigned short* __restrict__ W3T,
             const float* __restrict__ b3, unsigned short* __restrict__ Table,
             const int* __restrict__ cnt)
{
    __shared__ __align__(16) unsigned short lds[65536];
    const int mc = (*cnt + 255) & ~255;
    gemm256_body(lds, H2, W3T, b3, 2047, Table, 1024, 16, 2048, 0, mc, blockIdx.x, 3);
}

// ---------------- k_gather: one wave per batch row, 2-deep prefetch -------
__global__ __launch_bounds__(64)
void k_gather(const int* __restrict__ lengths, const int* __restrict__ slots,
              const unsigned short* __restrict__ Table, float* __restrict__ out)
{
    const int b    = blockIdx.x;
    const int lane = threadIdx.x;

    float acc[32];
#pragma unroll
    for (int j = 0; j < 32; ++j) acc[j] = 0.f;

    const int len = lengths[b];
    if (len > 0) {
        uint4 u0[4], u1[4];
        {
            const uint4* rp = (const uint4*)(Table + (size_t)slots[b * 20] * 2048);
#pragma unroll
            for (int c = 0; c < 4; ++c) u0[c] = rp[c * 64 + lane];
        }
        if (len > 1) {
            const uint4* rp = (const uint4*)(Table + (size_t)slots[b * 20 + 1] * 2048);
#pragma unroll
            for (int c = 0; c < 4; ++c) u1[c] = rp[c * 64 + lane];
        }
        for (int l = 0; l < len; ++l) {
            uint4 cu[4];
#pragma unroll
            for (int c = 0; c < 4; ++c) { cu[c] = u0[c]; u0[c] = u1[c]; }
            if (l + 2 < len) {                       // 2-deep prefetch
                const uint4* rp = (const uint4*)(Table + (size_t)slots[b * 20 + l + 2] * 2048);
#pragma unroll
                for (int c = 0; c < 4; ++c) u1[c] = rp[c * 64 + lane];
            }
            float v[32];
#pragma unroll
            for (int c = 0; c < 4; ++c) {
                v[c*8+0] = bf2f(cu[c].x & 0xffffu); v[c*8+1] = bf2f(cu[c].x >> 16);
                v[c*8+2] = bf2f(cu[c].y & 0xffffu); v[c*8+3] = bf2f(cu[c].y >> 16);
                v[c*8+4] = bf2f(cu[c].z & 0xffffu); v[c*8+5] = bf2f(cu[c].z >> 16);
                v[c*8+6] = bf2f(cu[c].w & 0xffffu); v[c*8+7] = bf2f(cu[c].w >> 16);
            }
            float s = 0.f;
#pragma unroll
            for (int j = 0; j < 32; ++j) s += v[j] * v[j];
#pragma unroll
            for (int off = 1; off < 64; off <<= 1) s += __shfl_xor(s, off, 64);
            const float invn = 1.0f / fmaxf(sqrtf(s), 1e-12f);
#pragma unroll
            for (int j = 0; j < 32; ++j) acc[j] += v[j] * invn;
        }
    }

    const size_t base = (size_t)b * 2047;
#pragma unroll
    for (int c = 0; c < 4; ++c) {
        const int col = (c * 64 + lane) * 8;
        if (c < 3 || lane != 63) {               // full 8 floats in-range
            *(float4*)&out[base + col]     = *(const float4*)&acc[c * 8];
            *(float4*)&out[base + col + 4] = *(const float4*)&acc[c * 8 + 4];
        } else {
#pragma unroll
            for (int j = 0; j < 7; ++j) out[base + col + j] = acc[c * 8 + j];
        }
    }
}

// ---------------- launch ----------------

extern "C" void kernel_launch(void* const* d_in, const int* in_sizes, int n_in,
                              void* d_out, int out_size, void* d_ws, size_t ws_size,
                              hipStream_t stream)
{
    const int*   ingrs   = (const int*)d_in[0];
    const int*   lengths = (const int*)d_in[1];
    const float* W1 = (const float*)d_in[2];
    const float* b1 = (const float*)d_in[3];
    const float* W2 = (const float*)d_in[4];
    const float* b2 = (const float*)d_in[5];
    const float* W3 = (const float*)d_in[6];
    const float* b3 = (const float*)d_in[7];
    float* out = (float*)d_out;

    char* ws = (char*)d_ws;
    unsigned short* A1    = (unsigned short*)(ws);
    unsigned short* H2    = (unsigned short*)(ws + 30801920);
    unsigned short* Table = (unsigned short*)(ws + 92405760);
    unsigned short* W2T   = (unsigned short*)(ws + 215613440);
    unsigned short* W3T   = (unsigned short*)(ws + 216662016);
    int*            flags = (int*)(ws + 220856320);
    int*            remap = (int*)(ws + 220976320);
    int*            cnt   = (int*)(ws + 221096320);
    int*            slots = (int*)(ws + 221216448);

    k_mark  <<<(4096 * 20 + 255) / 256, 256, 0, stream>>>(ingrs, lengths, flags, cnt);
    k_assign<<<(VOCAB + 255) / 256, 256, 0, stream>>>(flags, remap, cnt);
    // a1c (15000) | W2T (128) | W3T (512) | slots (320)
    k_prep<<<15960, 256, 0, stream>>>(W1, b1, flags, remap, A1, W2, W2T,
                                      W3, W3T, ingrs, lengths, slots);
    // GEMM1 (256^2 4-phase): H2 = relu(A1 @ W2 + b2)
    k_gemm1<<<G_MT * 4, 512, 0, stream>>>(A1, W2T, b2, H2, cnt);
    // GEMM2 (256^2 4-phase): Table = H2 @ W3 + b3
    k_gemm2<<<G_MT * 8, 512, 0, stream>>>(H2, W3T, b3, Table, cnt);

    k_gather<<<4096, 64, 0, stream>>>(lengths, slots, Table, out);
}